// Round 7
// baseline (1175.285 us; speedup 1.0000x reference)
//
#include <hip/hip_runtime.h>
#include <cmath>

#define HH 542
#define KH 271
#define NPIX (HH*HH)          // 293764
#define BB 8
#define CC3 3
#define NCH (BB*CC3)          // 24 real channels
#define NP 12                 // 12 packed complex planes
#define MROWS (NP*HH)         // 6504 complex rows per pass
#define KSZ 31
#define KRAD 15
#define NF 8
#define FS 3

#define NSPLIT 2
#define NGRP 40               // 20 re + 20 im groups of 16 v1
#define BTSZ (NGRP*NSPLIT*17*512)  // shorts per fragment-ordered B-table

typedef __attribute__((ext_vector_type(8))) short short8v;
typedef __attribute__((ext_vector_type(4))) float float4v;

static __device__ __forceinline__ float2 cmul(float2 a, float2 b) {
    return make_float2(a.x*b.x - a.y*b.y, a.x*b.y + a.y*b.x);
}

static __device__ __forceinline__ void pair_chans(int p, int& n1, int& n2) {
    if (p < 8) { n1 = 3*p;     n2 = 3*p + 1; }
    else       { int q = p-8; n1 = 6*q + 2; n2 = 6*q + 5; }
}

// ROUNDED 2-way bf16 split of two adjacent values (x=low short, y=high short).
// round-half-away via +0x8000 before truncate; residual <= 2^-18 relative.
static __device__ __forceinline__ void split2_pack_pair(float x, float y,
        unsigned& p0, unsigned& p1) {
    unsigned ux = __float_as_uint(x), uy = __float_as_uint(y);
    unsigned hx0 = (ux + 0x8000u) & 0xffff0000u;
    unsigned hy0 = (uy + 0x8000u) & 0xffff0000u;
    float rx = x - __uint_as_float(hx0);
    float ry = y - __uint_as_float(hy0);
    unsigned hx1 = (__float_as_uint(rx) + 0x8000u) & 0xffff0000u;
    unsigned hy1 = (__float_as_uint(ry) + 0x8000u) & 0xffff0000u;
    p0 = (hx0 >> 16) | hy0;
    p1 = (hx1 >> 16) | hy1;
}

// ---------------- tables: tw542 + fragment-ordered rounded-2-split bf16 B tables.
// Bt[((g*2+s)*17+step)*512 + lane*8 + j] = split_s of B'[n][k'], n=(g%20)*16+(lane&15)
// (g<20: re-part, g>=20: im-part), k' = step*32 + (lane>>4)*8 + j
__global__ void gen_tables(float2* tw542, short* Btf, short* Bti) {
    int idx = blockIdx.x*blockDim.x + threadIdx.x;
    const float PI2 = 6.283185307179586f;
    if (idx < HH) {
        float ang = -PI2*(float)idx/(float)HH;
        float s, c; sincosf(ang, &s, &c);
        tw542[idx] = make_float2(c, s);
    }
    if (idx >= BTSZ) return;
    int j    = idx & 7;
    int lane = (idx >> 3) & 63;
    int rem  = idx >> 9;
    int step = rem % 17;
    int rem2 = rem / 17;
    int s    = rem2 % NSPLIT;
    int g    = rem2 / NSPLIT;
    if (g >= NGRP) return;
    int o  = (g >= 20) ? 1 : 0;
    int v1 = (g - 20*o)*16 + (lane & 15);
    int kq = step*32 + (lane >> 4)*8 + j;
    int kidx = kq >> 1, c = kq & 1;
    float wre = 0.f, wim = 0.f;
    if (v1 < KH && kidx < KH) {
        int r = (kidx*v1) % KH;
        float ang = -PI2*(float)r/(float)KH;
        float sn, cs; sincosf(ang, &sn, &cs);
        wre = cs; wim = sn;
    }
    float vf = (o==0) ? ((c==0) ? wre : -wim) : ((c==0) ?  wim : wre);
    float vi = (o==0) ? ((c==0) ? wre :  wim) : ((c==0) ? -wim : wre);
    {
        unsigned u = __float_as_uint(vf);
        unsigned h0 = (u + 0x8000u) & 0xffff0000u;
        float r1 = vf - __uint_as_float(h0);
        unsigned h1 = (__float_as_uint(r1) + 0x8000u) & 0xffff0000u;
        Btf[idx] = (short)(((s==0) ? h0 : h1) >> 16);
    }
    {
        unsigned u = __float_as_uint(vi);
        unsigned h0 = (u + 0x8000u) & 0xffff0000u;
        float r1 = vi - __uint_as_float(h0);
        unsigned h1 = (__float_as_uint(r1) + 0x8000u) & 0xffff0000u;
        Bti[idx] = (short)(((s==0) ? h0 : h1) >> 16);
    }
}

// ---------------- edgetaper alpha vectors (closed-form autocorrelation)
__global__ void alpha_kernel(const float* __restrict__ kk, float* __restrict__ valpha) {
    int b = blockIdx.x;
    int t = threadIdx.x;
    __shared__ float proj[2][KSZ];
    __shared__ float ac[2][KSZ];
    const float* kb = kk + b*KSZ*KSZ;
    if (t < KSZ) {
        float s = 0;
        for (int j = 0; j < KSZ; j++) s += kb[t*KSZ + j];
        proj[0][t] = s;
    } else if (t >= 32 && t < 32+KSZ) {
        int j = t - 32;
        float s = 0;
        for (int i = 0; i < KSZ; i++) s += kb[i*KSZ + j];
        proj[1][j] = s;
    }
    __syncthreads();
    if (t < KSZ) {
        float s0 = 0, s1 = 0;
        for (int m = 0; m + t < KSZ; m++) {
            s0 += proj[0][m]*proj[0][m+t];
            s1 += proj[1][m]*proj[1][m+t];
        }
        ac[0][t] = s0; ac[1][t] = s1;
    }
    __syncthreads();
    float inv0 = 1.0f/ac[0][0];
    float inv1 = 1.0f/ac[1][0];
    for (int d = t; d < HH; d += blockDim.x) {
        for (int a = 0; a < 2; a++) {
            float z;
            if (d <= 30)                   z = ac[a][d];
            else if (d >= 511 && d <= 540) z = ac[a][541-d];
            else if (d == 541)             z = ac[a][0];
            else                           z = 0.0f;
            valpha[(b*2 + a)*HH + d] = 1.0f - z*(a ? inv1 : inv0);
        }
    }
}

// ---------------- Dk = psf2otf(k) via two small DFT stages.
// Twiddle via register rotation recurrence (w *= tw[step]) instead of per-iter
// table gather.
__global__ void dk_stage1(const float* __restrict__ kk, const float2* __restrict__ tw,
                          float2* __restrict__ T1) {
    int idx = blockIdx.x*blockDim.x + threadIdx.x;
    if (idx >= BB*KSZ*HH) return;
    int v  = idx % HH;
    int bm = idx / HH;
    int m  = bm % KSZ;
    int b  = bm / KSZ;
    const float* kb = kk + (b*KSZ + m)*KSZ;
    float2 w  = tw[(KRAD*(HH - v)) % HH];
    float2 ru = tw[v];
    float2 acc = make_float2(0.f, 0.f);
    for (int n = 0; n < KSZ; n++) {
        float kv = kb[n];
        acc.x = fmaf(kv, w.x, acc.x);
        acc.y = fmaf(kv, w.y, acc.y);
        float wx = w.x*ru.x - w.y*ru.y;
        float wy = w.x*ru.y + w.y*ru.x;
        w = make_float2(wx, wy);
    }
    T1[idx] = acc;
}

// u-tile of 8; w[uu] rotated by ru[uu]=tw[u] each m step; only load in the
// m-loop is the coalesced t1 stream. grid = b(8) x ut(68) x vchunk(3).
#define UT2 8
__global__ void dk_stage2(const float2* __restrict__ T1, const float2* __restrict__ tw,
                          float2* __restrict__ Dk) {
    int bid = blockIdx.x;
    int vc = bid % 3;
    int rem = bid / 3;
    int ut = rem % 68;
    int b  = rem / 68;
    int v = vc*256 + threadIdx.x;
    if (v >= HH) return;
    int u0 = ut*UT2;
    float2 acc[UT2], w[UT2], ru[UT2];
    #pragma unroll
    for (int uu = 0; uu < UT2; uu++) {
        int u = u0 + uu;
        int uc = (u < HH) ? u : 0;
        acc[uu] = make_float2(0.f, 0.f);
        w[uu]  = tw[(KRAD*(HH - uc)) % HH];
        ru[uu] = tw[uc];
    }
    const float2* t1 = T1 + (size_t)b*KSZ*HH + v;
    for (int m = 0; m < KSZ; m++) {
        float2 t = t1[(size_t)m*HH];
        #pragma unroll
        for (int uu = 0; uu < UT2; uu++) {
            acc[uu].x = fmaf(t.x, w[uu].x, fmaf(-t.y, w[uu].y, acc[uu].x));
            acc[uu].y = fmaf(t.x, w[uu].y, fmaf( t.y, w[uu].x, acc[uu].y));
            float wx = w[uu].x*ru[uu].x - w[uu].y*ru[uu].y;
            float wy = w[uu].x*ru[uu].y + w[uu].y*ru[uu].x;
            w[uu] = make_float2(wx, wy);
        }
    }
    #pragma unroll
    for (int uu = 0; uu < UT2; uu++) {
        int u = u0 + uu;
        if (u < HH) Dk[(size_t)b*NPIX + (size_t)u*HH + v] = acc[uu];
    }
}

// ---------------- Dg_sum[c][u][v] = exp(lam)*sum_f |DFT(filt[f,c])|^2 (mod-free)
__global__ void dgs_kernel(const float* __restrict__ filt, const float* __restrict__ lamp,
                           const float2* __restrict__ tw, float* __restrict__ Dgs) {
    int uv = blockIdx.x*blockDim.x + threadIdx.x;
    if (uv >= NPIX) return;
    int u = uv / HH;
    int v = uv - u*HH;
    float el = expf(lamp[0]);
    float2 wu[3], wv[3];
    wu[0] = tw[u ? HH-u : 0]; wu[1] = make_float2(1.f,0.f); wu[2] = tw[u];
    wv[0] = tw[v ? HH-v : 0]; wv[1] = make_float2(1.f,0.f); wv[2] = tw[v];
    float2 ph[3][3];
    #pragma unroll
    for (int m = 0; m < 3; m++)
        #pragma unroll
        for (int n = 0; n < 3; n++)
            ph[m][n] = cmul(wu[m], wv[n]);
    for (int c = 0; c < CC3; c++) {
        float s = 0.f;
        for (int f = 0; f < NF; f++) {
            float2 acc = make_float2(0.f, 0.f);
            const float* fp = filt + ((f*CC3 + c)*FS)*FS;
            #pragma unroll
            for (int m = 0; m < 3; m++)
                #pragma unroll
                for (int n = 0; n < 3; n++) {
                    float fv = fp[m*3+n];
                    acc.x = fmaf(fv, ph[m][n].x, acc.x);
                    acc.y = fmaf(fv, ph[m][n].y, acc.y);
                }
            s = fmaf(acc.x, acc.x, fmaf(acc.y, acc.y, s));
        }
        Dgs[c*NPIX + uv] = s*el;
    }
}

// ---------------- edge-replicate pad + pack pairs
__global__ void pad_pack(const float* __restrict__ y, float* __restrict__ R0,
                         float2* __restrict__ CA) {
    int idx = blockIdx.x*blockDim.x + threadIdx.x;
    if (idx >= NP*NPIX) return;
    int uv = idx % NPIX;
    int p  = idx / NPIX;
    int n1, n2; pair_chans(p, n1, n2);
    int i = uv / HH, j = uv - i*HH;
    int yi = min(max(i - KRAD, 0), 511);
    int yj = min(max(j - KRAD, 0), 511);
    int yo = yi*512 + yj;
    float v1 = y[(size_t)n1*262144 + yo];
    float v2 = y[(size_t)n2*262144 + yo];
    R0[(size_t)n1*NPIX + uv] = v1;
    R0[(size_t)n2*NPIX + uv] = v2;
    CA[idx] = make_float2(v1, v2);
}

// ---------------- Hermitian unpack, per-channel multiply, repack.
__global__ void specmul(const float2* __restrict__ CA, const float2* __restrict__ Dk,
                        const float* __restrict__ Dgs, float2* __restrict__ CB, int mode) {
    int idx = blockIdx.x*blockDim.x + threadIdx.x;
    if (idx >= NP*NPIX) return;
    int uv = idx % NPIX;
    int p  = idx / NPIX;
    int n1, n2; pair_chans(p, n1, n2);
    int b1 = n1/3, c1 = n1 - 3*b1;
    int b2 = n2/3, c2 = n2 - 3*b2;
    int i = uv / HH, j = uv - i*HH;
    int ni = i ? HH - i : 0;
    int nj = j ? HH - j : 0;
    float2 Z  = CA[(size_t)p*NPIX + uv];
    float2 Zm = CA[(size_t)p*NPIX + ni*HH + nj];
    float2 F1 = make_float2(0.5f*(Z.x + Zm.x), 0.5f*(Z.y - Zm.y));
    float2 F2 = make_float2(0.5f*(Z.y + Zm.y), 0.5f*(Zm.x - Z.x));
    float2 d1 = Dk[(size_t)b1*NPIX + uv];
    float2 d2 = Dk[(size_t)b2*NPIX + uv];
    float2 M1, M2;
    if (mode == 0) {
        M1 = d1; M2 = d2;
    } else {
        float o1 = 1.0f/(d1.x*d1.x + d1.y*d1.y + Dgs[(size_t)c1*NPIX + uv]);
        float o2 = 1.0f/(d2.x*d2.x + d2.y*d2.y + Dgs[(size_t)c2*NPIX + uv]);
        M1 = make_float2(d1.x*o1, -d1.y*o1);
        M2 = make_float2(d2.x*o2, -d2.y*o2);
    }
    float2 W1 = cmul(M1, F1);
    float2 W2 = cmul(M2, F2);
    CB[idx] = make_float2(W1.x - W2.y, W1.y + W2.x);
}

// ---------------- MFMA DFT pass: rounded-2-split, 3 products, wide-N.
// TLP-DOUBLED variant of the round-3 template: block = 16 complex rows x 64
// v1 (4 waves split along v1, each 32 M-rows x 16 v1 -> acc[2][2] = 16 VGPR).
// Grid 407x5 = 2035 -> ~8 blocks/CU = 8 waves/SIMD (was 4): every structural
// barrier experiment (r5 single-barrier, r6 BK=64) was null with all pipes at
// ~25-30%, pointing at convoyed 4-wave TLP as the real limiter. B is
// single-buffered (issued at step-top; staging+barrier covers L2 latency) to
// keep regs <= 64 for the 8-waves/SIMD occupancy tier. LDS 9216 B.
__global__ void __launch_bounds__(256, 8)
fft_mfma(const float2* __restrict__ Ain, float2* __restrict__ Aout,
         const short* __restrict__ Bt, const float2* __restrict__ tw542,
         const float* __restrict__ valp, float* __restrict__ R0,
         float* __restrict__ outbuf, float scale, int conjtw, int mode)
{
    __shared__ char smem[9216];           // staging 2x2560 B; Ts 64x9 float4 = 9216 B (union)
    short* As = (short*)smem;
    float4* Tsf = (float4*)smem;
    const int APL = 32*40;                // shorts per split plane (32 M-rows x 40)

    int id = blockIdx.x;
    int xcd = id & 7, jj = id >> 3;
    int lin = xcd*255 + jj;
    if (lin >= 2035) return;
    int by = lin / 5, bx = lin - 5*by;    // by 0..406 (16-row tiles), bx 0..4 (64 v1)

    int tid = threadIdx.x;
    int arow = tid >> 4, ai8 = tid & 15;  // 16 complex rows, 16 threads/row
    int wid = tid >> 6, lane = tid & 63;
    int l15 = lane & 15, quad = lane >> 4;

    int aoff0 = l15*40 + quad*8;          // all waves read all 32 M-rows

    // per-wave B groups: re = bx*4+wid, im = 20 + bx*4+wid
    const short* pB[2];
    #pragma unroll
    for (int ct = 0; ct < 2; ct++) {
        int grp = (ct ? 20 : 0) + bx*4 + wid;
        pB[ct] = Bt + (size_t)grp*(NSPLIT*17*512) + lane*8;
    }

    float4v acc[2][2];   // [mt][re/im]
    #pragma unroll
    for (int mt = 0; mt < 2; mt++)
        #pragma unroll
        for (int ct = 0; ct < 2; ct++)
            acc[mt][ct] = (float4v)(0.f);

    float4 regA[2];              // [buf] (one float4 = 2 complex samples)
    short8v bf[2][2];            // [ct][split] single-buffered
    const float4 z4 = make_float4(0.f,0.f,0.f,0.f);

    int rowg = by*16 + arow;
    bool rvld = rowg < MROWS;
    const float4* rp = (const float4*)Ain + (size_t)(rvld ? rowg : 0)*271;

    auto loadA = [&](int buf, int step) {
        int i0 = step*16 + ai8;
        regA[buf] = (rvld && i0 < 271) ? rp[i0] : z4;
    };
    auto loadB = [&](int step) {
        #pragma unroll
        for (int ct = 0; ct < 2; ct++)
            #pragma unroll
            for (int s = 0; s < NSPLIT; s++)
                bf[ct][s] = *(const short8v*)(pB[ct] + ((s*17 + step) << 9));
    };

    loadA(0, 0);

    #pragma unroll 2
    for (int step = 0; step < 17; step++) {
        int cur = step & 1, nxt = cur ^ 1;
        loadB(step);                      // issued early; used after barrier
        // stage A tile into LDS with rounded 2-way bf16 split:
        // even sample -> M-row 2*arow, odd sample -> M-row 2*arow+1
        {
            int off = (2*arow)*40 + 2*ai8;
            float4 f = regA[cur];
            unsigned e0, e1, o0, o1;
            split2_pack_pair(f.x, f.y, e0, e1);
            split2_pack_pair(f.z, f.w, o0, o1);
            *(unsigned*)(As + 0*APL + off)      = e0;
            *(unsigned*)(As + 1*APL + off)      = e1;
            *(unsigned*)(As + 0*APL + off + 40) = o0;
            *(unsigned*)(As + 1*APL + off + 40) = o1;
        }
        __syncthreads();

        if (step + 1 < 17) loadA(nxt, step + 1);

        #pragma unroll
        for (int sa = 0; sa < 2; sa++) {
            short8v af[2];
            #pragma unroll
            for (int mt = 0; mt < 2; mt++)
                af[mt] = *(const short8v*)(As + sa*APL + aoff0 + mt*16*40);
            #pragma unroll
            for (int sb = 0; sb + sa < 2; sb++)
                #pragma unroll
                for (int mt = 0; mt < 2; mt++)
                    #pragma unroll
                    for (int ct = 0; ct < 2; ct++)
                        acc[mt][ct] = __builtin_amdgcn_mfma_f32_16x16x32_bf16(
                            af[mt], bf[ct][sb], acc[mt][ct], 0, 0, 0);
        }
        __syncthreads();
    }

    // ---- epilogue: twiddle combine, LDS transpose (64 v1 x 16 cols), float4 stores
    float2 tg;
    {
        int v1g = (bx*4 + wid)*16 + l15;
        tg = tw542[(v1g < HH) ? v1g : 0];
        if (conjtw) tg.y = -tg.y;
    }

    int lane8 = tid & 7;                  // col-pair index 0..7
    int rrow = tid >> 3;                  // 0..31
    int r0 = by*16 + 2*lane8;             // even complex col; float4 never straddles plane
    bool rok = r0 < MROWS;
    int plane = rok ? (r0 / HH) : 0;
    int colg = r0 - plane*HH;
    int n1, n2; pair_chans(plane, n1, n2);
    int b1 = n1/3, b2 = n2/3;

    #pragma unroll
    for (int half = 0; half < 2; half++) {
        __syncthreads();
        #pragma unroll
        for (int mt = 0; mt < 2; mt++) {
            float2 v[2];
            #pragma unroll
            for (int pr = 0; pr < 2; pr++) {
                float Ere = acc[mt][0][2*pr], Ore = acc[mt][0][2*pr+1];
                float Eim = acc[mt][1][2*pr], Oim = acc[mt][1][2*pr+1];
                float tOre = tg.x*Ore - tg.y*Oim;
                float tOim = tg.x*Oim + tg.y*Ore;
                v[pr] = (half == 0)
                    ? make_float2((Ere + tOre)*scale, (Eim + tOim)*scale)
                    : make_float2((Ere - tOre)*scale, (Eim - tOim)*scale);
            }
            int v1loc = wid*16 + l15;
            int uu = mt*4 + quad;         // float4 unit = source-col pair
            Tsf[v1loc*9 + uu] = make_float4(v[0].x, v[0].y, v[1].x, v[1].y);
        }
        __syncthreads();
        #pragma unroll
        for (int it = 0; it < 2; it++) {
            int v1loc = rrow + it*32;
            int v1g2 = bx*64 + v1loc;
            if (v1g2 >= KH || !rok) continue;
            int v1 = v1g2 + (half ? KH : 0);
            float4 f = Tsf[v1loc*9 + lane8];
            size_t sp = (size_t)v1*HH + colg;
            if (mode == 0) {
                *(float4*)(Aout + (size_t)plane*NPIX + sp) = f;
            } else if (mode == 1) {
                float ar1 = valp[b1*2*HH + v1];
                float ar2 = valp[b2*2*HH + v1];
                float ac1a = valp[(b1*2+1)*HH + colg];
                float ac1b = valp[(b1*2+1)*HH + colg + 1];
                float ac2a = valp[(b2*2+1)*HH + colg];
                float ac2b = valp[(b2*2+1)*HH + colg + 1];
                float2* p1 = (float2*)(R0 + (size_t)n1*NPIX + sp);
                float2* p2 = (float2*)(R0 + (size_t)n2*NPIX + sp);
                float2 o1 = *p1, o2 = *p2;
                float nv1a = fmaf(ar1*ac1a, o1.x - f.x, f.x);
                float nv1b = fmaf(ar1*ac1b, o1.y - f.z, f.z);
                float nv2a = fmaf(ar2*ac2a, o2.x - f.y, f.y);
                float nv2b = fmaf(ar2*ac2b, o2.y - f.w, f.w);
                *p1 = make_float2(nv1a, nv1b);
                *p2 = make_float2(nv2a, nv2b);
                *(float4*)(Aout + (size_t)plane*NPIX + sp) =
                    make_float4(nv1a, nv2a, nv1b, nv2b);
            } else {
                *(float2*)(outbuf + (size_t)n1*NPIX + sp) = make_float2(f.x, f.z);
                *(float2*)(outbuf + (size_t)n2*NPIX + sp) = make_float2(f.y, f.w);
            }
        }
    }
}

extern "C" void kernel_launch(void* const* d_in, const int* in_sizes, int n_in,
                              void* d_out, int out_size, void* d_ws, size_t ws_size,
                              hipStream_t stream) {
    const float* y    = (const float*)d_in[0];
    const float* k    = (const float*)d_in[1];
    const float* lam  = (const float*)d_in[2];
    const float* filt = (const float*)d_in[3];
    float* out = (float*)d_out;

    char* base = (char*)d_ws;
    size_t off = 0;
    auto alloc = [&](size_t bytes) {
        void* p = base + off;
        off = (off + bytes + 511) & ~(size_t)511;
        return p;
    };
    float2* CA   = (float2*)alloc(sizeof(float2)*(size_t)NP*NPIX);
    float2* CB   = (float2*)alloc(sizeof(float2)*(size_t)NP*NPIX);
    float*  R0   = (float*) alloc(sizeof(float)*(size_t)NCH*NPIX);
    float2* Dk   = (float2*)alloc(sizeof(float2)*(size_t)BB*NPIX);
    float2* T1   = (float2*)alloc(sizeof(float2)*(size_t)BB*KSZ*HH);
    float*  Dgs  = (float*) alloc(sizeof(float)*(size_t)CC3*NPIX);
    short*  Btf  = (short*) alloc(sizeof(short)*(size_t)BTSZ);
    short*  Bti  = (short*) alloc(sizeof(short)*(size_t)BTSZ);
    float2* tw   = (float2*)alloc(sizeof(float2)*(size_t)HH);
    float*  valp = (float*) alloc(sizeof(float)*(size_t)BB*2*HH);
    (void)ws_size; (void)in_sizes; (void)n_in; (void)out_size;

    const int TPB = 256;
    auto nb = [](long n) { return (int)((n + 255)/256); };

    gen_tables<<<nb((long)BTSZ), TPB, 0, stream>>>(tw, Btf, Bti);
    alpha_kernel<<<BB, 64, 0, stream>>>(k, valp);
    dk_stage1<<<nb((long)BB*KSZ*HH), TPB, 0, stream>>>(k, tw, T1);
    dk_stage2<<<8*68*3, TPB, 0, stream>>>(T1, tw, Dk);
    dgs_kernel<<<nb((long)NPIX), TPB, 0, stream>>>(filt, lam, tw, Dgs);
    pad_pack<<<nb((long)NP*NPIX), TPB, 0, stream>>>(y, R0, CA);

    const int FG = 2040;  // 8 XCDs x 255 (2035 active) -> ~8 blocks/CU
    const float isc = 1.0f/(float)HH;
    float2 *S = CA, *T = CB;
    fft_mfma<<<FG, TPB, 0, stream>>>(S, T, Btf, tw, valp, R0, out, 1.0f, 0, 0);
    fft_mfma<<<FG, TPB, 0, stream>>>(T, S, Btf, tw, valp, R0, out, 1.0f, 0, 0);
    for (int it = 0; it < 3; it++) {
        specmul<<<nb((long)NP*NPIX), TPB, 0, stream>>>(S, Dk, Dgs, T, 0);
        fft_mfma<<<FG, TPB, 0, stream>>>(T, S, Bti, tw, valp, R0, out, isc, 1, 0);
        fft_mfma<<<FG, TPB, 0, stream>>>(S, T, Bti, tw, valp, R0, out, isc, 1, 1);
        fft_mfma<<<FG, TPB, 0, stream>>>(T, S, Btf, tw, valp, R0, out, 1.0f, 0, 0);
        fft_mfma<<<FG, TPB, 0, stream>>>(S, T, Btf, tw, valp, R0, out, 1.0f, 0, 0);
        float2* tmp = S; S = T; T = tmp;
    }
    specmul<<<nb((long)NP*NPIX), TPB, 0, stream>>>(S, Dk, Dgs, T, 1);
    fft_mfma<<<FG, TPB, 0, stream>>>(T, S, Bti, tw, valp, R0, out, isc, 1, 0);
    fft_mfma<<<FG, TPB, 0, stream>>>(S, T, Bti, tw, valp, R0, out, isc, 1, 2);
}

// Round 8
// 749.288 us; speedup vs baseline: 1.5685x; 1.5685x over previous
//
#include <hip/hip_runtime.h>
#include <cmath>

#define HH 542
#define KH 271
#define NPIX (HH*HH)          // 293764 logical pixels
#define RS 544                // padded row stride (complex) for internal buffers: 4352 B = 68 cache lines
#define PPIX (HH*RS)          // padded plane size
#define BB 8
#define CC3 3
#define NCH (BB*CC3)          // 24 real channels
#define NP 12                 // 12 packed complex planes
#define MROWS (NP*HH)         // 6504 complex rows per pass
#define KSZ 31
#define KRAD 15
#define NF 8
#define FS 3

#define NSPLIT 2
#define NGRP 40               // 20 re + 20 im groups of 16 v1
#define BTSZ (NGRP*NSPLIT*17*512)  // shorts per fragment-ordered B-table

typedef __attribute__((ext_vector_type(8))) short short8v;
typedef __attribute__((ext_vector_type(4))) float float4v;

static __device__ __forceinline__ float2 cmul(float2 a, float2 b) {
    return make_float2(a.x*b.x - a.y*b.y, a.x*b.y + a.y*b.x);
}

static __device__ __forceinline__ void pair_chans(int p, int& n1, int& n2) {
    if (p < 8) { n1 = 3*p;     n2 = 3*p + 1; }
    else       { int q = p-8; n1 = 6*q + 2; n2 = 6*q + 5; }
}

// ROUNDED 2-way bf16 split of two adjacent values (x=low short, y=high short).
// round-half-away via +0x8000 before truncate; residual <= 2^-18 relative.
static __device__ __forceinline__ void split2_pack_pair(float x, float y,
        unsigned& p0, unsigned& p1) {
    unsigned ux = __float_as_uint(x), uy = __float_as_uint(y);
    unsigned hx0 = (ux + 0x8000u) & 0xffff0000u;
    unsigned hy0 = (uy + 0x8000u) & 0xffff0000u;
    float rx = x - __uint_as_float(hx0);
    float ry = y - __uint_as_float(hy0);
    unsigned hx1 = (__float_as_uint(rx) + 0x8000u) & 0xffff0000u;
    unsigned hy1 = (__float_as_uint(ry) + 0x8000u) & 0xffff0000u;
    p0 = (hx0 >> 16) | hy0;
    p1 = (hx1 >> 16) | hy1;
}

// ---------------- tables: tw542 + fragment-ordered rounded-2-split bf16 B tables.
__global__ void gen_tables(float2* tw542, short* Btf, short* Bti) {
    int idx = blockIdx.x*blockDim.x + threadIdx.x;
    const float PI2 = 6.283185307179586f;
    if (idx < HH) {
        float ang = -PI2*(float)idx/(float)HH;
        float s, c; sincosf(ang, &s, &c);
        tw542[idx] = make_float2(c, s);
    }
    if (idx >= BTSZ) return;
    int j    = idx & 7;
    int lane = (idx >> 3) & 63;
    int rem  = idx >> 9;
    int step = rem % 17;
    int rem2 = rem / 17;
    int s    = rem2 % NSPLIT;
    int g    = rem2 / NSPLIT;
    if (g >= NGRP) return;
    int o  = (g >= 20) ? 1 : 0;
    int v1 = (g - 20*o)*16 + (lane & 15);
    int kq = step*32 + (lane >> 4)*8 + j;
    int kidx = kq >> 1, c = kq & 1;
    float wre = 0.f, wim = 0.f;
    if (v1 < KH && kidx < KH) {
        int r = (kidx*v1) % KH;
        float ang = -PI2*(float)r/(float)KH;
        float sn, cs; sincosf(ang, &sn, &cs);
        wre = cs; wim = sn;
    }
    float vf = (o==0) ? ((c==0) ? wre : -wim) : ((c==0) ?  wim : wre);
    float vi = (o==0) ? ((c==0) ? wre :  wim) : ((c==0) ? -wim : wre);
    {
        unsigned u = __float_as_uint(vf);
        unsigned h0 = (u + 0x8000u) & 0xffff0000u;
        float r1 = vf - __uint_as_float(h0);
        unsigned h1 = (__float_as_uint(r1) + 0x8000u) & 0xffff0000u;
        Btf[idx] = (short)(((s==0) ? h0 : h1) >> 16);
    }
    {
        unsigned u = __float_as_uint(vi);
        unsigned h0 = (u + 0x8000u) & 0xffff0000u;
        float r1 = vi - __uint_as_float(h0);
        unsigned h1 = (__float_as_uint(r1) + 0x8000u) & 0xffff0000u;
        Bti[idx] = (short)(((s==0) ? h0 : h1) >> 16);
    }
}

// ---------------- edgetaper alpha vectors (closed-form autocorrelation)
__global__ void alpha_kernel(const float* __restrict__ kk, float* __restrict__ valpha) {
    int b = blockIdx.x;
    int t = threadIdx.x;
    __shared__ float proj[2][KSZ];
    __shared__ float ac[2][KSZ];
    const float* kb = kk + b*KSZ*KSZ;
    if (t < KSZ) {
        float s = 0;
        for (int j = 0; j < KSZ; j++) s += kb[t*KSZ + j];
        proj[0][t] = s;
    } else if (t >= 32 && t < 32+KSZ) {
        int j = t - 32;
        float s = 0;
        for (int i = 0; i < KSZ; i++) s += kb[i*KSZ + j];
        proj[1][j] = s;
    }
    __syncthreads();
    if (t < KSZ) {
        float s0 = 0, s1 = 0;
        for (int m = 0; m + t < KSZ; m++) {
            s0 += proj[0][m]*proj[0][m+t];
            s1 += proj[1][m]*proj[1][m+t];
        }
        ac[0][t] = s0; ac[1][t] = s1;
    }
    __syncthreads();
    float inv0 = 1.0f/ac[0][0];
    float inv1 = 1.0f/ac[1][0];
    for (int d = t; d < HH; d += blockDim.x) {
        for (int a = 0; a < 2; a++) {
            float z;
            if (d <= 30)                   z = ac[a][d];
            else if (d >= 511 && d <= 540) z = ac[a][541-d];
            else if (d == 541)             z = ac[a][0];
            else                           z = 0.0f;
            valpha[(b*2 + a)*HH + d] = 1.0f - z*(a ? inv1 : inv0);
        }
    }
}

// ---------------- Dk = psf2otf(k) via two small DFT stages.
// Twiddle via register rotation recurrence (w *= tw[step]).
__global__ void dk_stage1(const float* __restrict__ kk, const float2* __restrict__ tw,
                          float2* __restrict__ T1) {
    int idx = blockIdx.x*blockDim.x + threadIdx.x;
    if (idx >= BB*KSZ*HH) return;
    int v  = idx % HH;
    int bm = idx / HH;
    int m  = bm % KSZ;
    int b  = bm / KSZ;
    const float* kb = kk + (b*KSZ + m)*KSZ;
    float2 w  = tw[(KRAD*(HH - v)) % HH];
    float2 ru = tw[v];
    float2 acc = make_float2(0.f, 0.f);
    for (int n = 0; n < KSZ; n++) {
        float kv = kb[n];
        acc.x = fmaf(kv, w.x, acc.x);
        acc.y = fmaf(kv, w.y, acc.y);
        float wx = w.x*ru.x - w.y*ru.y;
        float wy = w.x*ru.y + w.y*ru.x;
        w = make_float2(wx, wy);
    }
    T1[idx] = acc;
}

// u-tile of 8; w[uu] rotated by ru[uu]=tw[u] each m step.
#define UT2 8
__global__ void dk_stage2(const float2* __restrict__ T1, const float2* __restrict__ tw,
                          float2* __restrict__ Dk) {
    int bid = blockIdx.x;
    int vc = bid % 3;
    int rem = bid / 3;
    int ut = rem % 68;
    int b  = rem / 68;
    int v = vc*256 + threadIdx.x;
    if (v >= HH) return;
    int u0 = ut*UT2;
    float2 acc[UT2], w[UT2], ru[UT2];
    #pragma unroll
    for (int uu = 0; uu < UT2; uu++) {
        int u = u0 + uu;
        int uc = (u < HH) ? u : 0;
        acc[uu] = make_float2(0.f, 0.f);
        w[uu]  = tw[(KRAD*(HH - uc)) % HH];
        ru[uu] = tw[uc];
    }
    const float2* t1 = T1 + (size_t)b*KSZ*HH + v;
    for (int m = 0; m < KSZ; m++) {
        float2 t = t1[(size_t)m*HH];
        #pragma unroll
        for (int uu = 0; uu < UT2; uu++) {
            acc[uu].x = fmaf(t.x, w[uu].x, fmaf(-t.y, w[uu].y, acc[uu].x));
            acc[uu].y = fmaf(t.x, w[uu].y, fmaf( t.y, w[uu].x, acc[uu].y));
            float wx = w[uu].x*ru[uu].x - w[uu].y*ru[uu].y;
            float wy = w[uu].x*ru[uu].y + w[uu].y*ru[uu].x;
            w[uu] = make_float2(wx, wy);
        }
    }
    #pragma unroll
    for (int uu = 0; uu < UT2; uu++) {
        int u = u0 + uu;
        if (u < HH) Dk[(size_t)b*NPIX + (size_t)u*HH + v] = acc[uu];
    }
}

// ---------------- Dg_sum[c][u][v] = exp(lam)*sum_f |DFT(filt[f,c])|^2 (unpadded)
__global__ void dgs_kernel(const float* __restrict__ filt, const float* __restrict__ lamp,
                           const float2* __restrict__ tw, float* __restrict__ Dgs) {
    int uv = blockIdx.x*blockDim.x + threadIdx.x;
    if (uv >= NPIX) return;
    int u = uv / HH;
    int v = uv - u*HH;
    float el = expf(lamp[0]);
    float2 wu[3], wv[3];
    wu[0] = tw[u ? HH-u : 0]; wu[1] = make_float2(1.f,0.f); wu[2] = tw[u];
    wv[0] = tw[v ? HH-v : 0]; wv[1] = make_float2(1.f,0.f); wv[2] = tw[v];
    float2 ph[3][3];
    #pragma unroll
    for (int m = 0; m < 3; m++)
        #pragma unroll
        for (int n = 0; n < 3; n++)
            ph[m][n] = cmul(wu[m], wv[n]);
    for (int c = 0; c < CC3; c++) {
        float s = 0.f;
        for (int f = 0; f < NF; f++) {
            float2 acc = make_float2(0.f, 0.f);
            const float* fp = filt + ((f*CC3 + c)*FS)*FS;
            #pragma unroll
            for (int m = 0; m < 3; m++)
                #pragma unroll
                for (int n = 0; n < 3; n++) {
                    float fv = fp[m*3+n];
                    acc.x = fmaf(fv, ph[m][n].x, acc.x);
                    acc.y = fmaf(fv, ph[m][n].y, acc.y);
                }
            s = fmaf(acc.x, acc.x, fmaf(acc.y, acc.y, s));
        }
        Dgs[c*NPIX + uv] = s*el;
    }
}

// ---------------- edge-replicate pad + pack pairs (PADDED stride-544 outputs)
__global__ void pad_pack(const float* __restrict__ y, float* __restrict__ R0,
                         float2* __restrict__ CA) {
    int idx = blockIdx.x*blockDim.x + threadIdx.x;
    if (idx >= NP*NPIX) return;
    int uv = idx % NPIX;
    int p  = idx / NPIX;
    int n1, n2; pair_chans(p, n1, n2);
    int i = uv / HH, j = uv - i*HH;
    int yi = min(max(i - KRAD, 0), 511);
    int yj = min(max(j - KRAD, 0), 511);
    int yo = yi*512 + yj;
    float v1 = y[(size_t)n1*262144 + yo];
    float v2 = y[(size_t)n2*262144 + yo];
    size_t sp = (size_t)i*RS + j;
    R0[(size_t)n1*PPIX + sp] = v1;
    R0[(size_t)n2*PPIX + sp] = v2;
    CA[(size_t)p*PPIX + sp] = make_float2(v1, v2);
}

// ---------------- Hermitian unpack, per-channel multiply, repack (PADDED CA/CB).
__global__ void specmul(const float2* __restrict__ CA, const float2* __restrict__ Dk,
                        const float* __restrict__ Dgs, float2* __restrict__ CB, int mode) {
    int idx = blockIdx.x*blockDim.x + threadIdx.x;
    if (idx >= NP*NPIX) return;
    int uv = idx % NPIX;
    int p  = idx / NPIX;
    int n1, n2; pair_chans(p, n1, n2);
    int b1 = n1/3, c1 = n1 - 3*b1;
    int b2 = n2/3, c2 = n2 - 3*b2;
    int i = uv / HH, j = uv - i*HH;
    int ni = i ? HH - i : 0;
    int nj = j ? HH - j : 0;
    float2 Z  = CA[(size_t)p*PPIX + (size_t)i*RS + j];
    float2 Zm = CA[(size_t)p*PPIX + (size_t)ni*RS + nj];
    float2 F1 = make_float2(0.5f*(Z.x + Zm.x), 0.5f*(Z.y - Zm.y));
    float2 F2 = make_float2(0.5f*(Z.y + Zm.y), 0.5f*(Zm.x - Z.x));
    float2 d1 = Dk[(size_t)b1*NPIX + uv];
    float2 d2 = Dk[(size_t)b2*NPIX + uv];
    float2 M1, M2;
    if (mode == 0) {
        M1 = d1; M2 = d2;
    } else {
        float o1 = 1.0f/(d1.x*d1.x + d1.y*d1.y + Dgs[(size_t)c1*NPIX + uv]);
        float o2 = 1.0f/(d2.x*d2.x + d2.y*d2.y + Dgs[(size_t)c2*NPIX + uv]);
        M1 = make_float2(d1.x*o1, -d1.y*o1);
        M2 = make_float2(d2.x*o2, -d2.y*o2);
    }
    float2 W1 = cmul(M1, F1);
    float2 W2 = cmul(M2, F2);
    CB[(size_t)p*PPIX + (size_t)i*RS + j] = make_float2(W1.x - W2.y, W1.y + W2.x);
}

// ---------------- MFMA DFT pass: rounded-2-split, 3 products, wide-N.
// EXACT round-3 structure (best verified 44.9us: 2-barrier lockstep, A/B
// prefetch 1-deep issued between barriers) with PADDED row stride RS=544 for
// Ain/Aout/R0: rows 64B-aligned -> transposed epilogue writes are full-line
// (was 48B-offset rows: 2 partial 64B lines per 256B span, cross-XCD RMW ->
// WRITE_SIZE 62MB for 28MB of data, FETCH +7MB). outbuf keeps true 542 stride.
__global__ void __launch_bounds__(256, 4)
fft_mfma(const float2* __restrict__ Ain, float2* __restrict__ Aout,
         const short* __restrict__ Bt, const float2* __restrict__ tw542,
         const float* __restrict__ valp, float* __restrict__ R0,
         float* __restrict__ outbuf, float scale, int conjtw, int mode)
{
    __shared__ char smem[17408];          // staging 10240 B; Ts 64x17 float4 = 17408 B
    short* As = (short*)smem;
    float4* Tsf = (float4*)smem;
    const int APL = 64*40;                // shorts per split plane (64 real rows x 40)

    int id = blockIdx.x;
    int xcd = id & 7, jj = id >> 3;
    int lin = xcd*128 + jj;
    if (lin >= 1020) return;
    int by = lin / 5, bx = lin - 5*by;    // by 0..203 (32-row tiles), bx 0..4 (64 v1)

    int tid = threadIdx.x;
    int arow = tid >> 3, ai4 = tid & 7;   // 32 complex rows, 8 threads/row
    int wid = tid >> 6, lane = tid & 63;
    int l15 = lane & 15, quad = lane >> 4;

    int aoff0 = l15*40 + quad*8;          // all waves read all 64 real rows

    // per-wave B groups: re = bx*4+wid, im = 20 + bx*4+wid
    const short* pB[2];
    #pragma unroll
    for (int ct = 0; ct < 2; ct++) {
        int grp = (ct ? 20 : 0) + bx*4 + wid;
        pB[ct] = Bt + (size_t)grp*(NSPLIT*17*512) + lane*8;
    }

    float4v acc[4][2];   // [mt][re/im]
    #pragma unroll
    for (int mt = 0; mt < 4; mt++)
        #pragma unroll
        for (int ct = 0; ct < 2; ct++)
            acc[mt][ct] = (float4v)(0.f);

    float4 regA[2][2];           // [buf][pair]
    short8v bf[2][2][2];         // [buf][ct][split]
    const float4 z4 = make_float4(0.f,0.f,0.f,0.f);

    int rowg = by*32 + arow;
    bool rvld = rowg < MROWS;
    const float4* rp = (const float4*)Ain + (size_t)(rvld ? rowg : 0)*(RS/2);

    auto loadA = [&](int buf, int step) {
        int i0 = step*16 + 2*ai4;
        regA[buf][0] = (rvld && i0     < 271) ? rp[i0]   : z4;
        regA[buf][1] = (rvld && i0 + 1 < 271) ? rp[i0+1] : z4;
    };
    auto loadB = [&](int buf, int step) {
        #pragma unroll
        for (int ct = 0; ct < 2; ct++)
            #pragma unroll
            for (int s = 0; s < NSPLIT; s++)
                bf[buf][ct][s] = *(const short8v*)(pB[ct] + ((s*17 + step) << 9));
    };

    loadA(0, 0); loadB(0, 0);

    #pragma unroll 2
    for (int step = 0; step < 17; step++) {
        int cur = step & 1, nxt = cur ^ 1;
        // stage A tile into LDS with rounded 2-way bf16 split
        {
            int rl = 2*arow;
            int offE = rl*40 + 4*ai4;
            float4 f0 = regA[cur][0], f1 = regA[cur][1];
            unsigned e0a,e1a, e0b,e1b;
            split2_pack_pair(f0.x, f0.y, e0a, e1a);
            split2_pack_pair(f1.x, f1.y, e0b, e1b);
            *(uint2*)(As + 0*APL + offE) = make_uint2(e0a, e0b);
            *(uint2*)(As + 1*APL + offE) = make_uint2(e1a, e1b);
            unsigned o0a,o1a, o0b,o1b;
            split2_pack_pair(f0.z, f0.w, o0a, o1a);
            split2_pack_pair(f1.z, f1.w, o0b, o1b);
            int offO = offE + 40;
            *(uint2*)(As + 0*APL + offO) = make_uint2(o0a, o0b);
            *(uint2*)(As + 1*APL + offO) = make_uint2(o1a, o1b);
        }
        __syncthreads();

        if (step + 1 < 17) { loadA(nxt, step+1); loadB(nxt, step+1); }

        #pragma unroll
        for (int sa = 0; sa < 2; sa++) {
            short8v af[4];
            #pragma unroll
            for (int mt = 0; mt < 4; mt++)
                af[mt] = *(const short8v*)(As + sa*APL + aoff0 + mt*16*40);
            #pragma unroll
            for (int sb = 0; sb + sa < 2; sb++)
                #pragma unroll
                for (int mt = 0; mt < 4; mt++)
                    #pragma unroll
                    for (int ct = 0; ct < 2; ct++)
                        acc[mt][ct] = __builtin_amdgcn_mfma_f32_16x16x32_bf16(
                            af[mt], bf[cur][ct][sb], acc[mt][ct], 0, 0, 0);
        }
        __syncthreads();
    }

    // ---- epilogue: twiddle combine, LDS transpose (64 v1 x 32 cols), float4 stores
    float2 tg;
    {
        int v1g = (bx*4 + wid)*16 + l15;
        tg = tw542[(v1g < HH) ? v1g : 0];
        if (conjtw) tg.y = -tg.y;
    }

    int lane16 = tid & 15;
    int rrow = tid >> 4;                  // 0..15
    int r0 = by*32 + 2*lane16;            // even complex col; float4 never straddles plane
    bool rok = r0 < MROWS;
    int plane = rok ? (r0 / HH) : 0;
    int colg = r0 - plane*HH;
    int n1, n2; pair_chans(plane, n1, n2);
    int b1 = n1/3, b2 = n2/3;

    #pragma unroll
    for (int half = 0; half < 2; half++) {
        __syncthreads();
        #pragma unroll
        for (int mt = 0; mt < 4; mt++) {
            float2 v[2];
            #pragma unroll
            for (int pr = 0; pr < 2; pr++) {
                float Ere = acc[mt][0][2*pr], Ore = acc[mt][0][2*pr+1];
                float Eim = acc[mt][1][2*pr], Oim = acc[mt][1][2*pr+1];
                float tOre = tg.x*Ore - tg.y*Oim;
                float tOim = tg.x*Oim + tg.y*Ore;
                v[pr] = (half == 0)
                    ? make_float2((Ere + tOre)*scale, (Eim + tOim)*scale)
                    : make_float2((Ere - tOre)*scale, (Eim - tOim)*scale);
            }
            int v1loc = wid*16 + l15;
            int uu = mt*4 + quad;         // float4 unit = source-col pair
            Tsf[v1loc*17 + uu] = make_float4(v[0].x, v[0].y, v[1].x, v[1].y);
        }
        __syncthreads();
        #pragma unroll
        for (int it = 0; it < 4; it++) {
            int v1loc = rrow + it*16;
            int v1g2 = bx*64 + v1loc;
            if (v1g2 >= KH || !rok) continue;
            int v1 = v1g2 + (half ? KH : 0);
            float4 f = Tsf[v1loc*17 + lane16];
            size_t sp = (size_t)v1*RS + colg;       // padded stride (64B-aligned rows)
            if (mode == 0) {
                *(float4*)(Aout + (size_t)plane*PPIX + sp) = f;
            } else if (mode == 1) {
                float ar1 = valp[b1*2*HH + v1];
                float ar2 = valp[b2*2*HH + v1];
                float ac1a = valp[(b1*2+1)*HH + colg];
                float ac1b = valp[(b1*2+1)*HH + colg + 1];
                float ac2a = valp[(b2*2+1)*HH + colg];
                float ac2b = valp[(b2*2+1)*HH + colg + 1];
                float2* p1 = (float2*)(R0 + (size_t)n1*PPIX + sp);
                float2* p2 = (float2*)(R0 + (size_t)n2*PPIX + sp);
                float2 o1 = *p1, o2 = *p2;
                float nv1a = fmaf(ar1*ac1a, o1.x - f.x, f.x);
                float nv1b = fmaf(ar1*ac1b, o1.y - f.z, f.z);
                float nv2a = fmaf(ar2*ac2a, o2.x - f.y, f.y);
                float nv2b = fmaf(ar2*ac2b, o2.y - f.w, f.w);
                *p1 = make_float2(nv1a, nv1b);
                *p2 = make_float2(nv2a, nv2b);
                *(float4*)(Aout + (size_t)plane*PPIX + sp) =
                    make_float4(nv1a, nv2a, nv1b, nv2b);
            } else {
                size_t so = (size_t)v1*HH + colg;   // TRUE 542 stride for final output
                *(float2*)(outbuf + (size_t)n1*NPIX + so) = make_float2(f.x, f.z);
                *(float2*)(outbuf + (size_t)n2*NPIX + so) = make_float2(f.y, f.w);
            }
        }
    }
}

extern "C" void kernel_launch(void* const* d_in, const int* in_sizes, int n_in,
                              void* d_out, int out_size, void* d_ws, size_t ws_size,
                              hipStream_t stream) {
    const float* y    = (const float*)d_in[0];
    const float* k    = (const float*)d_in[1];
    const float* lam  = (const float*)d_in[2];
    const float* filt = (const float*)d_in[3];
    float* out = (float*)d_out;

    char* base = (char*)d_ws;
    size_t off = 0;
    auto alloc = [&](size_t bytes) {
        void* p = base + off;
        off = (off + bytes + 511) & ~(size_t)511;
        return p;
    };
    float2* CA   = (float2*)alloc(sizeof(float2)*(size_t)NP*PPIX);
    float2* CB   = (float2*)alloc(sizeof(float2)*(size_t)NP*PPIX);
    float*  R0   = (float*) alloc(sizeof(float)*(size_t)NCH*PPIX);
    float2* Dk   = (float2*)alloc(sizeof(float2)*(size_t)BB*NPIX);
    float2* T1   = (float2*)alloc(sizeof(float2)*(size_t)BB*KSZ*HH);
    float*  Dgs  = (float*) alloc(sizeof(float)*(size_t)CC3*NPIX);
    short*  Btf  = (short*) alloc(sizeof(short)*(size_t)BTSZ);
    short*  Bti  = (short*) alloc(sizeof(short)*(size_t)BTSZ);
    float2* tw   = (float2*)alloc(sizeof(float2)*(size_t)HH);
    float*  valp = (float*) alloc(sizeof(float)*(size_t)BB*2*HH);
    (void)ws_size; (void)in_sizes; (void)n_in; (void)out_size;

    const int TPB = 256;
    auto nb = [](long n) { return (int)((n + 255)/256); };

    gen_tables<<<nb((long)BTSZ), TPB, 0, stream>>>(tw, Btf, Bti);
    alpha_kernel<<<BB, 64, 0, stream>>>(k, valp);
    dk_stage1<<<nb((long)BB*KSZ*HH), TPB, 0, stream>>>(k, tw, T1);
    dk_stage2<<<8*68*3, TPB, 0, stream>>>(T1, tw, Dk);
    dgs_kernel<<<nb((long)NPIX), TPB, 0, stream>>>(filt, lam, tw, Dgs);
    pad_pack<<<nb((long)NP*NPIX), TPB, 0, stream>>>(y, R0, CA);

    const int FG = 1024;  // 8 XCDs x 128 (1020 active) -> 4 blocks/CU
    const float isc = 1.0f/(float)HH;
    float2 *S = CA, *T = CB;
    fft_mfma<<<FG, TPB, 0, stream>>>(S, T, Btf, tw, valp, R0, out, 1.0f, 0, 0);
    fft_mfma<<<FG, TPB, 0, stream>>>(T, S, Btf, tw, valp, R0, out, 1.0f, 0, 0);
    for (int it = 0; it < 3; it++) {
        specmul<<<nb((long)NP*NPIX), TPB, 0, stream>>>(S, Dk, Dgs, T, 0);
        fft_mfma<<<FG, TPB, 0, stream>>>(T, S, Bti, tw, valp, R0, out, isc, 1, 0);
        fft_mfma<<<FG, TPB, 0, stream>>>(S, T, Bti, tw, valp, R0, out, isc, 1, 1);
        fft_mfma<<<FG, TPB, 0, stream>>>(T, S, Btf, tw, valp, R0, out, 1.0f, 0, 0);
        fft_mfma<<<FG, TPB, 0, stream>>>(S, T, Btf, tw, valp, R0, out, 1.0f, 0, 0);
        float2* tmp = S; S = T; T = tmp;
    }
    specmul<<<nb((long)NP*NPIX), TPB, 0, stream>>>(S, Dk, Dgs, T, 1);
    fft_mfma<<<FG, TPB, 0, stream>>>(T, S, Bti, tw, valp, R0, out, isc, 1, 0);
    fft_mfma<<<FG, TPB, 0, stream>>>(S, T, Bti, tw, valp, R0, out, isc, 1, 2);
}